// Round 1
// baseline (559.712 us; speedup 1.0000x reference)
//
#include <hip/hip_runtime.h>

#define NB 8
#define CIN 256
#define LL 4096
#define CQ 32
#define CV 256

typedef __attribute__((ext_vector_type(8))) short bf16x8;
typedef __attribute__((ext_vector_type(4))) float f32x4;

__device__ __forceinline__ unsigned short f2bf(float f) {
    unsigned u = __float_as_uint(f);
    u += 0x7fff + ((u >> 16) & 1);
    return (unsigned short)(u >> 16);
}
__device__ __forceinline__ float bf2f(unsigned short h) {
    return __uint_as_float(((unsigned)h) << 16);
}

// ---------------- K1: fused QKV projection (fp32 VALU, bf16 out) ----------------
// grid (8, 10, 8) block 256. Each block: 32 output rows x 512 spatial positions.
__global__ __launch_bounds__(256) void k_qkv(
    const float* __restrict__ x, const float* __restrict__ Wq,
    const float* __restrict__ Wk, const float* __restrict__ Wv,
    unsigned short* __restrict__ q, unsigned short* __restrict__ k,
    unsigned short* __restrict__ v)
{
    __shared__ float wlds[32 * 256];
    const int n = blockIdx.z, rg = blockIdx.y, lt = blockIdx.x, t = threadIdx.x;
    const float* src;
    unsigned short* dst;
    if (rg == 0)      { src = Wq;                      dst = q + n * CQ * LL; }
    else if (rg == 1) { src = Wk;                      dst = k + n * CQ * LL; }
    else              { src = Wv + (rg - 2) * 32 * CIN;
                        dst = v + (n * CV + (rg - 2) * 32) * LL; }
    #pragma unroll
    for (int i = 0; i < 32; i++) wlds[i * 256 + t] = src[i * 256 + t];
    __syncthreads();
    const int w = t >> 6, lane = t & 63;
    const int l = lt * 512 + lane * 8;
    const float* xp = x + n * CIN * LL + l;

    float acc[8][8];
    #pragma unroll
    for (int r = 0; r < 8; r++)
        #pragma unroll
        for (int j = 0; j < 8; j++) acc[r][j] = 0.f;

    for (int c0 = 0; c0 < CIN; c0 += 4) {
        float xs[4][8];
        #pragma unroll
        for (int cc = 0; cc < 4; cc++) {
            const float4* p = (const float4*)(xp + (c0 + cc) * LL);
            float4 a = p[0], b = p[1];
            xs[cc][0] = a.x; xs[cc][1] = a.y; xs[cc][2] = a.z; xs[cc][3] = a.w;
            xs[cc][4] = b.x; xs[cc][5] = b.y; xs[cc][6] = b.z; xs[cc][7] = b.w;
        }
        #pragma unroll
        for (int r = 0; r < 8; r++) {
            const float4 wv4 = *(const float4*)&wlds[(w * 8 + r) * 256 + c0];
            const float wc[4] = {wv4.x, wv4.y, wv4.z, wv4.w};
            #pragma unroll
            for (int cc = 0; cc < 4; cc++)
                #pragma unroll
                for (int j = 0; j < 8; j++)
                    acc[r][j] += wc[cc] * xs[cc][j];
        }
    }
    #pragma unroll
    for (int r = 0; r < 8; r++) {
        bf16x8 s;
        #pragma unroll
        for (int j = 0; j < 8; j++) s[j] = (short)f2bf(acc[r][j]);
        *(bf16x8*)(dst + (w * 8 + r) * LL + l) = s;
    }
}

// ---------------- K2: softmax denominators rl[n][i] = 1/sum_j exp(e_ij) --------
// grid (64, 8) block 256. Block: 64 i-rows, all 4096 j.
__global__ __launch_bounds__(256) void k_rowsum(
    const unsigned short* __restrict__ q, const unsigned short* __restrict__ kk,
    float* __restrict__ rl)
{
    __shared__ float qlds[64][36];   // [i][c], +4 pad
    __shared__ float red[64];
    const int n = blockIdx.y, i0 = blockIdx.x * 64, t = threadIdx.x;
    {
        const int i = t & 63, w = t >> 6;
        float tmp[8];
        #pragma unroll
        for (int cc = 0; cc < 8; cc++)
            tmp[cc] = bf2f(q[(n * CQ + w * 8 + cc) * LL + i0 + i]);
        #pragma unroll
        for (int cc = 0; cc < 8; cc++) qlds[i][w * 8 + cc] = tmp[cc];
    }
    if (t < 64) red[t] = 0.f;
    __syncthreads();
    const int iq = (t >> 6) * 16 + (t & 1) * 8;   // 8 i's: iq..iq+7
    const int jb = ((t >> 1) & 31) * 8;           // 8 j's within 256-j tile
    float ls[8] = {0.f, 0.f, 0.f, 0.f, 0.f, 0.f, 0.f, 0.f};
    for (int jt = 0; jt < 16; jt++) {
        const int j = jt * 256 + jb;
        float d[8][8];
        #pragma unroll
        for (int ii = 0; ii < 8; ii++)
            #pragma unroll
            for (int jj = 0; jj < 8; jj++) d[ii][jj] = 0.f;
        #pragma unroll 2
        for (int c0 = 0; c0 < CQ; c0 += 4) {
            float kv[4][8];
            #pragma unroll
            for (int cc = 0; cc < 4; cc++) {
                const bf16x8 kraw = *(const bf16x8*)&kk[(n * CQ + c0 + cc) * LL + j];
                #pragma unroll
                for (int jj = 0; jj < 8; jj++) kv[cc][jj] = bf2f((unsigned short)kraw[jj]);
            }
            #pragma unroll
            for (int ii = 0; ii < 8; ii++) {
                const float4 q4 = *(const float4*)&qlds[iq + ii][c0];
                const float qa[4] = {q4.x, q4.y, q4.z, q4.w};
                #pragma unroll
                for (int cc = 0; cc < 4; cc++)
                    #pragma unroll
                    for (int jj = 0; jj < 8; jj++)
                        d[ii][jj] += qa[cc] * kv[cc][jj];
            }
        }
        #pragma unroll
        for (int ii = 0; ii < 8; ii++) {
            float s = 0.f;
            #pragma unroll
            for (int jj = 0; jj < 8; jj++) s += __expf(d[ii][jj]);
            ls[ii] += s;
        }
    }
    #pragma unroll
    for (int ii = 0; ii < 8; ii++) atomicAdd(&red[iq + ii], ls[ii]);
    __syncthreads();
    if (t < 64) rl[n * LL + i0 + t] = 1.0f / red[t];
}

// ---------------- K3: fused attention core (MFMA bf16) -------------------------
// o[v][j] = sum_i V[v][i] * exp(e_ij) * rl_i.  grid (64, 8) block 256 (4 waves).
// Block: j-tile of 64, all 256 v-rows; loop i in chunks of 64.
__global__ __launch_bounds__(256) void k_attn(
    const unsigned short* __restrict__ q, const unsigned short* __restrict__ kk,
    const unsigned short* __restrict__ v, const float* __restrict__ rl,
    unsigned short* __restrict__ o)
{
    __shared__ unsigned short klds[64][40];  // [j][c], +8 pad (16B-aligned rows)
    __shared__ unsigned short qlds[64][40];  // [i][c]
    __shared__ unsigned short plds[64][72];  // [j][i], +8 pad
    __shared__ float rllds[64];
    const int n = blockIdx.y, j0 = blockIdx.x * 64, t = threadIdx.x;
    const int w = t >> 6, lane = t & 63, lid = lane & 15, quad = lane >> 4;

    {   // stage k tile transposed: klds[j][c]
        bf16x8 tmp;
        #pragma unroll
        for (int cc = 0; cc < 8; cc++)
            tmp[cc] = (short)kk[(n * CQ + w * 8 + cc) * LL + j0 + lane];
        *(bf16x8*)&klds[lane][w * 8] = tmp;
    }
    __syncthreads();
    bf16x8 bk[4];   // B-frags of K, one per 16-col group, live all iterations
    #pragma unroll
    for (int nt = 0; nt < 4; nt++)
        bk[nt] = *(const bf16x8*)&klds[nt * 16 + lid][quad * 8];

    const f32x4 fzero = {0.f, 0.f, 0.f, 0.f};
    f32x4 acc[4][4];
    #pragma unroll
    for (int mt = 0; mt < 4; mt++)
        #pragma unroll
        for (int nt = 0; nt < 4; nt++) acc[mt][nt] = fzero;

    for (int ic = 0; ic < 64; ic++) {
        const int i0 = ic * 64;
        {   // stage q tile transposed: qlds[i][c]
            bf16x8 tmp;
            #pragma unroll
            for (int cc = 0; cc < 8; cc++)
                tmp[cc] = (short)q[(n * CQ + w * 8 + cc) * LL + i0 + lane];
            *(bf16x8*)&qlds[lane][w * 8] = tmp;
        }
        if (t < 64) rllds[t] = rl[n * LL + i0 + t];
        __syncthreads();
        // E phase: wave w computes E rows [16w,16w+16) x all 64 j. A=q^T, B=k.
        const bf16x8 aq = *(const bf16x8*)&qlds[w * 16 + lid][quad * 8];
        #pragma unroll
        for (int nt = 0; nt < 4; nt++) {
            f32x4 e = __builtin_amdgcn_mfma_f32_16x16x32_bf16(aq, bk[nt], fzero, 0, 0, 0);
            // D layout: row(i_local) = 16w + quad*4 + reg, col(j_local) = nt*16 + lid
            ushort4 pp;
            pp.x = f2bf(__expf(e[0]) * rllds[w * 16 + quad * 4 + 0]);
            pp.y = f2bf(__expf(e[1]) * rllds[w * 16 + quad * 4 + 1]);
            pp.z = f2bf(__expf(e[2]) * rllds[w * 16 + quad * 4 + 2]);
            pp.w = f2bf(__expf(e[3]) * rllds[w * 16 + quad * 4 + 3]);
            *(ushort4*)&plds[nt * 16 + lid][w * 16 + quad * 4] = pp;
        }
        __syncthreads();
        // O phase: wave w handles v rows [64w, 64w+64). A=V (global), B=P (LDS).
        #pragma unroll
        for (int h = 0; h < 2; h++) {
            bf16x8 bp[4];
            #pragma unroll
            for (int nt = 0; nt < 4; nt++)
                bp[nt] = *(const bf16x8*)&plds[nt * 16 + lid][h * 32 + quad * 8];
            #pragma unroll
            for (int mt = 0; mt < 4; mt++) {
                const bf16x8 av = *(const bf16x8*)
                    &v[(n * CV + w * 64 + mt * 16 + lid) * LL + i0 + h * 32 + quad * 8];
                #pragma unroll
                for (int nt = 0; nt < 4; nt++)
                    acc[mt][nt] = __builtin_amdgcn_mfma_f32_16x16x32_bf16(av, bp[nt], acc[mt][nt], 0, 0, 0);
            }
        }
    }
    #pragma unroll
    for (int mt = 0; mt < 4; mt++)
        #pragma unroll
        for (int nt = 0; nt < 4; nt++)
            #pragma unroll
            for (int reg = 0; reg < 4; reg++)
                o[(n * CV + w * 64 + mt * 16 + quad * 4 + reg) * LL + j0 + nt * 16 + lid] =
                    f2bf(acc[mt][nt][reg]);
}

// ---------------- K5: output projection + gamma (fp32 VALU) --------------------
// grid (8, 8, 8) block 256. Block: 32 output rows x 512 spatial positions.
__global__ __launch_bounds__(256) void k_out(
    const unsigned short* __restrict__ o, const float* __restrict__ Wo,
    const float* __restrict__ gp, float* __restrict__ out)
{
    __shared__ float wlds[32 * 256];
    const int n = blockIdx.z, rg = blockIdx.y, lt = blockIdx.x, t = threadIdx.x;
    const float* src = Wo + rg * 32 * CV;
    #pragma unroll
    for (int i = 0; i < 32; i++) wlds[i * 256 + t] = src[i * 256 + t];
    __syncthreads();
    const float g = *gp;
    const int w = t >> 6, lane = t & 63;
    const int l = lt * 512 + lane * 8;
    const unsigned short* op = o + n * CV * LL + l;

    float acc[8][8];
    #pragma unroll
    for (int r = 0; r < 8; r++)
        #pragma unroll
        for (int j = 0; j < 8; j++) acc[r][j] = 0.f;

    for (int c0 = 0; c0 < CV; c0 += 4) {
        float xs[4][8];
        #pragma unroll
        for (int cc = 0; cc < 4; cc++) {
            const bf16x8 raw = *(const bf16x8*)(op + (c0 + cc) * LL);
            #pragma unroll
            for (int j = 0; j < 8; j++) xs[cc][j] = bf2f((unsigned short)raw[j]);
        }
        #pragma unroll
        for (int r = 0; r < 8; r++) {
            const float4 wv4 = *(const float4*)&wlds[(w * 8 + r) * 256 + c0];
            const float wc[4] = {wv4.x, wv4.y, wv4.z, wv4.w};
            #pragma unroll
            for (int cc = 0; cc < 4; cc++)
                #pragma unroll
                for (int j = 0; j < 8; j++)
                    acc[r][j] += wc[cc] * xs[cc][j];
        }
    }
    float* outp = out + (n * CIN + rg * 32 + w * 8) * LL + l;
    #pragma unroll
    for (int r = 0; r < 8; r++) {
        float4 a, b;
        a.x = g * acc[r][0]; a.y = g * acc[r][1]; a.z = g * acc[r][2]; a.w = g * acc[r][3];
        b.x = g * acc[r][4]; b.y = g * acc[r][5]; b.z = g * acc[r][6]; b.w = g * acc[r][7];
        *(float4*)(outp + r * LL) = a;
        *(float4*)(outp + r * LL + 4) = b;
    }
}

extern "C" void kernel_launch(void* const* d_in, const int* in_sizes, int n_in,
                              void* d_out, int out_size, void* d_ws, size_t ws_size,
                              hipStream_t stream) {
    const float* x     = (const float*)d_in[0];
    const float* Wq    = (const float*)d_in[1];
    const float* Wk    = (const float*)d_in[2];
    const float* Wv    = (const float*)d_in[3];
    const float* Wo    = (const float*)d_in[4];
    const float* gamma = (const float*)d_in[5];

    unsigned short* q = (unsigned short*)d_ws;     // 2 MB
    unsigned short* k = q + NB * CQ * LL;          // 2 MB
    unsigned short* v = k + NB * CQ * LL;          // 16 MB
    unsigned short* o = v + NB * CV * LL;          // 16 MB
    float* rl = (float*)(o + NB * CV * LL);        // 128 KB
    float* out = (float*)d_out;

    k_qkv  <<<dim3(8, 10, 8), 256, 0, stream>>>(x, Wq, Wk, Wv, q, k, v);
    k_rowsum<<<dim3(64, 8),    256, 0, stream>>>(q, k, rl);
    k_attn <<<dim3(64, 8),     256, 0, stream>>>(q, k, v, rl, o);
    k_out  <<<dim3(8, 8, 8),   256, 0, stream>>>(o, Wo, gamma, out);
}

// Round 2
// 306.528 us; speedup vs baseline: 1.8260x; 1.8260x over previous
//
#include <hip/hip_runtime.h>
#include <hip/hip_bf16.h>

#define NB 8
#define CIN 256
#define LL 4096
#define CQ 32
#define CV 256

typedef __attribute__((ext_vector_type(8))) short bf16x8;
typedef __attribute__((ext_vector_type(4))) float f32x4;

__device__ __forceinline__ unsigned short f2bf(float f) {
    union { __hip_bfloat16 h; unsigned short u; } c;
    c.h = __float2bfloat16(f);
    return c.u;
}
__device__ __forceinline__ unsigned int f2bf2(float a, float b) {
    union { __hip_bfloat162 h; unsigned int u; } c;
    float2 f; f.x = a; f.y = b;
    c.h = __float22bfloat162_rn(f);
    return c.u;
}
__device__ __forceinline__ float bf2f(unsigned short h) {
    return __uint_as_float(((unsigned)h) << 16);
}

// ---------------- K0: cast weights to bf16 -------------------------------------
// Wb rows 0..31 = Wq, 32..63 = Wk, 64..319 = Wv.  Wob = Wo.
__global__ __launch_bounds__(256) void k_wcast(
    const float* __restrict__ Wq, const float* __restrict__ Wk,
    const float* __restrict__ Wv, const float* __restrict__ Wo,
    unsigned short* __restrict__ Wb, unsigned short* __restrict__ Wob)
{
    const int row = blockIdx.x, t = threadIdx.x;
    if (row < 320) {
        const float* src = row < 32 ? Wq + row * 256
                         : row < 64 ? Wk + (row - 32) * 256
                                    : Wv + (row - 64) * 256;
        Wb[row * 256 + t] = f2bf(src[t]);
    } else {
        const int r2 = row - 320;
        Wob[r2 * 256 + t] = f2bf(Wo[r2 * 256 + t]);
    }
}

// ---------------- K1: fused QKV projection, MFMA bf16 --------------------------
// grid (64, 8): l-tile 64, batch n. 4 waves, each owns 80 output rows.
// q,k rows -> qkt[n][l][64] (transposed, A/B-frag-ready); v rows -> v[n][v][l].
__global__ __launch_bounds__(256) void k_qkv2(
    const float* __restrict__ x, const unsigned short* __restrict__ Wb,
    unsigned short* __restrict__ qkt, unsigned short* __restrict__ v)
{
    __shared__ unsigned short xlds[64][264];   // [l][c], stride 264 (132 dw)
    const int n = blockIdx.y, l0 = blockIdx.x * 64, t = threadIdx.x;
    const int w = t >> 6, lane = t & 63, lid = lane & 15, quad = lane >> 4;

    #pragma unroll
    for (int part = 0; part < 8; part++) {
        const int cbase = part * 32 + w * 8;
        float tmp[8];
        #pragma unroll
        for (int cc = 0; cc < 8; cc++)
            tmp[cc] = x[(n * CIN + cbase + cc) * LL + l0 + lane];
        bf16x8 s;
        #pragma unroll
        for (int cc = 0; cc < 8; cc++) s[cc] = (short)f2bf(tmp[cc]);
        *(bf16x8*)&xlds[lane][cbase] = s;
    }
    __syncthreads();

    const f32x4 fzero = {0.f, 0.f, 0.f, 0.f};
    f32x4 acc[5][4];
    #pragma unroll
    for (int mt = 0; mt < 5; mt++)
        #pragma unroll
        for (int nt = 0; nt < 4; nt++) acc[mt][nt] = fzero;

    for (int k0 = 0; k0 < 256; k0 += 32) {
        bf16x8 bx[4];
        #pragma unroll
        for (int nt = 0; nt < 4; nt++)
            bx[nt] = *(const bf16x8*)&xlds[nt * 16 + lid][k0 + quad * 8];
        #pragma unroll
        for (int mt = 0; mt < 5; mt++) {
            const bf16x8 wa = *(const bf16x8*)&Wb[(w * 80 + mt * 16 + lid) * 256 + k0 + quad * 8];
            #pragma unroll
            for (int nt = 0; nt < 4; nt++)
                acc[mt][nt] = __builtin_amdgcn_mfma_f32_16x16x32_bf16(wa, bx[nt], acc[mt][nt], 0, 0, 0);
        }
    }
    #pragma unroll
    for (int mt = 0; mt < 5; mt++)
        #pragma unroll
        for (int nt = 0; nt < 4; nt++)
            #pragma unroll
            for (int reg = 0; reg < 4; reg++) {
                const int r = w * 80 + mt * 16 + quad * 4 + reg;
                const int l = l0 + nt * 16 + lid;
                const unsigned short val = f2bf(acc[mt][nt][reg]);
                if (r < 64) qkt[(n * LL + l) * 64 + r] = val;     // q (c<32) / k (c>=32)
                else        v[(n * CV + (r - 64)) * LL + l] = val;
            }
}

// ---------------- K2: softmax denominators, MFMA bf16 --------------------------
// grid (64, 8): i-tile 64, n. Wave w covers j = w*64 + jt*256 slices.
__global__ __launch_bounds__(256) void k_rowsum2(
    const unsigned short* __restrict__ qkt, float* __restrict__ rl)
{
    __shared__ float red[64];
    const int n = blockIdx.y, i0 = blockIdx.x * 64, t = threadIdx.x;
    const int w = t >> 6, lane = t & 63, lid = lane & 15, quad = lane >> 4;
    if (t < 64) red[t] = 0.f;
    __syncthreads();

    bf16x8 aq[4];
    #pragma unroll
    for (int mt = 0; mt < 4; mt++)
        aq[mt] = *(const bf16x8*)&qkt[(n * LL + i0 + mt * 16 + lid) * 64 + quad * 8];

    const f32x4 fzero = {0.f, 0.f, 0.f, 0.f};
    float sums[4][4];
    #pragma unroll
    for (int mt = 0; mt < 4; mt++)
        #pragma unroll
        for (int reg = 0; reg < 4; reg++) sums[mt][reg] = 0.f;

    for (int jt = 0; jt < 16; jt++) {
        const int j0 = jt * 256 + w * 64;
        bf16x8 bk[4];
        #pragma unroll
        for (int nt = 0; nt < 4; nt++)
            bk[nt] = *(const bf16x8*)&qkt[(n * LL + j0 + nt * 16 + lid) * 64 + 32 + quad * 8];
        #pragma unroll
        for (int mt = 0; mt < 4; mt++)
            #pragma unroll
            for (int nt = 0; nt < 4; nt++) {
                f32x4 e = __builtin_amdgcn_mfma_f32_16x16x32_bf16(aq[mt], bk[nt], fzero, 0, 0, 0);
                sums[mt][0] += __expf(e[0]);
                sums[mt][1] += __expf(e[1]);
                sums[mt][2] += __expf(e[2]);
                sums[mt][3] += __expf(e[3]);
            }
    }
    #pragma unroll
    for (int mt = 0; mt < 4; mt++)
        #pragma unroll
        for (int reg = 0; reg < 4; reg++) {
            float s = sums[mt][reg];
            s += __shfl_xor(s, 1); s += __shfl_xor(s, 2);
            s += __shfl_xor(s, 4); s += __shfl_xor(s, 8);
            if (lid == 0) atomicAdd(&red[mt * 16 + quad * 4 + reg], s);
        }
    __syncthreads();
    if (t < 64) rl[n * LL + i0 + t] = 1.0f / red[t];
}

// ---------------- K3: fused attention core, MFMA bf16 --------------------------
// grid (64, 2, 8): j-tile 64, v-half, n. 4 waves; wave owns 32 v-rows.
// P tile in XOR-swizzled LDS (chunk ^= j&7, 16B chunks), no padding.
__global__ __launch_bounds__(256) void k_attn2(
    const unsigned short* __restrict__ qkt, const unsigned short* __restrict__ v,
    const float* __restrict__ rl, unsigned short* __restrict__ o)
{
    __shared__ unsigned short plds[64][64];    // [j][i], swizzled
    const int n = blockIdx.z, vh = blockIdx.y, j0 = blockIdx.x * 64, t = threadIdx.x;
    const int w = t >> 6, lane = t & 63, lid = lane & 15, quad = lane >> 4;
    const int xkey = lid & 7;

    bf16x8 bk[4];
    #pragma unroll
    for (int nt = 0; nt < 4; nt++)
        bk[nt] = *(const bf16x8*)&qkt[(n * LL + j0 + nt * 16 + lid) * 64 + 32 + quad * 8];

    const f32x4 fzero = {0.f, 0.f, 0.f, 0.f};
    f32x4 acc[2][4];
    #pragma unroll
    for (int mt = 0; mt < 2; mt++)
        #pragma unroll
        for (int nt = 0; nt < 4; nt++) acc[mt][nt] = fzero;

    for (int ic = 0; ic < 64; ic++) {
        const int i0 = ic * 64;
        const bf16x8 aq = *(const bf16x8*)&qkt[(n * LL + i0 + w * 16 + lid) * 64 + quad * 8];
        const float4 rl4 = *(const float4*)&rl[n * LL + i0 + w * 16 + quad * 4];
        __syncthreads();   // previous O-phase reads done before overwriting P
        #pragma unroll
        for (int nt = 0; nt < 4; nt++) {
            f32x4 e = __builtin_amdgcn_mfma_f32_16x16x32_bf16(aq, bk[nt], fzero, 0, 0, 0);
            const unsigned a01 = f2bf2(__expf(e[0]) * rl4.x, __expf(e[1]) * rl4.y);
            const unsigned a23 = f2bf2(__expf(e[2]) * rl4.z, __expf(e[3]) * rl4.w);
            const int chunk = (2 * w + (quad >> 1)) ^ xkey;
            unsigned* p = (unsigned*)&plds[nt * 16 + lid][chunk * 8 + (quad & 1) * 4];
            p[0] = a01; p[1] = a23;
        }
        __syncthreads();
        #pragma unroll
        for (int h = 0; h < 2; h++) {
            bf16x8 bp[4];
            #pragma unroll
            for (int nt = 0; nt < 4; nt++) {
                const int chunk = (4 * h + quad) ^ xkey;
                bp[nt] = *(const bf16x8*)&plds[nt * 16 + lid][chunk * 8];
            }
            #pragma unroll
            for (int mt = 0; mt < 2; mt++) {
                const bf16x8 av = *(const bf16x8*)
                    &v[(n * CV + vh * 128 + w * 32 + mt * 16 + lid) * LL + i0 + h * 32 + quad * 8];
                #pragma unroll
                for (int nt = 0; nt < 4; nt++)
                    acc[mt][nt] = __builtin_amdgcn_mfma_f32_16x16x32_bf16(av, bp[nt], acc[mt][nt], 0, 0, 0);
            }
        }
    }
    #pragma unroll
    for (int mt = 0; mt < 2; mt++)
        #pragma unroll
        for (int nt = 0; nt < 4; nt++)
            #pragma unroll
            for (int reg = 0; reg < 4; reg++)
                o[(n * CV + vh * 128 + w * 32 + mt * 16 + quad * 4 + reg) * LL + j0 + nt * 16 + lid] =
                    f2bf(acc[mt][nt][reg]);
}

// ---------------- K4: output projection + gamma, MFMA bf16 ---------------------
// grid (64, 8): l-tile 64, n. Wave owns 64 output rows.
__global__ __launch_bounds__(256) void k_out2(
    const unsigned short* __restrict__ o, const unsigned short* __restrict__ Wob,
    const float* __restrict__ gp, float* __restrict__ out)
{
    __shared__ unsigned short olds[64][264];   // [l][v]
    const int n = blockIdx.y, l0 = blockIdx.x * 64, t = threadIdx.x;
    const int w = t >> 6, lane = t & 63, lid = lane & 15, quad = lane >> 4;

    #pragma unroll
    for (int part = 0; part < 8; part++) {
        const int cbase = part * 32 + w * 8;
        bf16x8 s;
        #pragma unroll
        for (int cc = 0; cc < 8; cc++)
            s[cc] = (short)o[(n * CV + cbase + cc) * LL + l0 + lane];
        *(bf16x8*)&olds[lane][cbase] = s;
    }
    __syncthreads();

    const f32x4 fzero = {0.f, 0.f, 0.f, 0.f};
    f32x4 acc[4][4];
    #pragma unroll
    for (int mt = 0; mt < 4; mt++)
        #pragma unroll
        for (int nt = 0; nt < 4; nt++) acc[mt][nt] = fzero;

    for (int k0 = 0; k0 < 256; k0 += 32) {
        bf16x8 bo[4];
        #pragma unroll
        for (int nt = 0; nt < 4; nt++)
            bo[nt] = *(const bf16x8*)&olds[nt * 16 + lid][k0 + quad * 8];
        #pragma unroll
        for (int mt = 0; mt < 4; mt++) {
            const bf16x8 wa = *(const bf16x8*)&Wob[(w * 64 + mt * 16 + lid) * 256 + k0 + quad * 8];
            #pragma unroll
            for (int nt = 0; nt < 4; nt++)
                acc[mt][nt] = __builtin_amdgcn_mfma_f32_16x16x32_bf16(wa, bo[nt], acc[mt][nt], 0, 0, 0);
        }
    }
    const float g = *gp;
    #pragma unroll
    for (int mt = 0; mt < 4; mt++)
        #pragma unroll
        for (int nt = 0; nt < 4; nt++)
            #pragma unroll
            for (int reg = 0; reg < 4; reg++) {
                const int r = w * 64 + mt * 16 + quad * 4 + reg;
                out[(n * CIN + r) * LL + l0 + nt * 16 + lid] = g * acc[mt][nt][reg];
            }
}

extern "C" void kernel_launch(void* const* d_in, const int* in_sizes, int n_in,
                              void* d_out, int out_size, void* d_ws, size_t ws_size,
                              hipStream_t stream) {
    const float* x     = (const float*)d_in[0];
    const float* Wq    = (const float*)d_in[1];
    const float* Wk    = (const float*)d_in[2];
    const float* Wv    = (const float*)d_in[3];
    const float* Wo    = (const float*)d_in[4];
    const float* gamma = (const float*)d_in[5];

    unsigned short* qkt = (unsigned short*)d_ws;              // 8*4096*64   = 4 MB
    unsigned short* v   = qkt + (size_t)NB * LL * 64;         // 8*256*4096  = 16 MB
    unsigned short* o   = v + (size_t)NB * CV * LL;           // 16 MB
    unsigned short* Wb  = o + (size_t)NB * CV * LL;           // 320*256     = 160 KB
    unsigned short* Wob = Wb + 320 * 256;                     // 256*256     = 128 KB
    float* rl           = (float*)(Wob + 256 * 256);          // 8*4096*4    = 128 KB
    float* out = (float*)d_out;

    k_wcast  <<<dim3(576),      256, 0, stream>>>(Wq, Wk, Wv, Wo, Wb, Wob);
    k_qkv2   <<<dim3(64, 8),    256, 0, stream>>>(x, Wb, qkt, v);
    k_rowsum2<<<dim3(64, 8),    256, 0, stream>>>(qkt, rl);
    k_attn2  <<<dim3(64, 2, 8), 256, 0, stream>>>(qkt, v, rl, o);
    k_out2   <<<dim3(64, 8),    256, 0, stream>>>(o, Wob, gamma, out);
}

// Round 3
// 297.890 us; speedup vs baseline: 1.8789x; 1.0290x over previous
//
#include <hip/hip_runtime.h>
#include <hip/hip_bf16.h>

#define NB 8
#define CIN 256
#define LL 4096
#define CQ 32
#define CV 256

typedef __attribute__((ext_vector_type(8))) short bf16x8;
typedef __attribute__((ext_vector_type(4))) float f32x4;

__device__ __forceinline__ unsigned short f2bf(float f) {
    union { __hip_bfloat16 h; unsigned short u; } c;
    c.h = __float2bfloat16(f);
    return c.u;
}
__device__ __forceinline__ unsigned int f2bf2(float a, float b) {
    union { __hip_bfloat162 h; unsigned int u; } c;
    float2 f; f.x = a; f.y = b;
    c.h = __float22bfloat162_rn(f);
    return c.u;
}

// ---------------- K0: cast weights to bf16; Wq pre-scaled by log2(e) -----------
// Wb rows 0..31 = Wq*log2e, 32..63 = Wk, 64..319 = Wv.  Wob = Wo.
__global__ __launch_bounds__(256) void k_wcast(
    const float* __restrict__ Wq, const float* __restrict__ Wk,
    const float* __restrict__ Wv, const float* __restrict__ Wo,
    unsigned short* __restrict__ Wb, unsigned short* __restrict__ Wob)
{
    const float LOG2E = 1.4426950408889634f;
    const int row = blockIdx.x, t = threadIdx.x;
    if (row < 320) {
        float val;
        if (row < 32)      val = Wq[row * 256 + t] * LOG2E;
        else if (row < 64) val = Wk[(row - 32) * 256 + t];
        else               val = Wv[(row - 64) * 256 + t];
        Wb[row * 256 + t] = f2bf(val);
    } else {
        const int r2 = row - 320;
        Wob[r2 * 256 + t] = f2bf(Wo[r2 * 256 + t]);
    }
}

// ---------------- K1: fused QKV projection, MFMA bf16 --------------------------
// grid (64, 8). Wave w owns qk rows [w*16, w*16+16) and v rows [w*64, w*64+64).
// qk stored transposed via LDS: qkt[n][l][64]; v stored [n][v][l].
__global__ __launch_bounds__(256) void k_qkv2(
    const float* __restrict__ x, const unsigned short* __restrict__ Wb,
    unsigned short* __restrict__ qkt, unsigned short* __restrict__ v)
{
    __shared__ unsigned short xlds[64][264];   // [l][c]
    __shared__ unsigned short tr[64][72];      // [l][r], 144B rows (16B aligned)
    const int n = blockIdx.y, l0 = blockIdx.x * 64, t = threadIdx.x;
    const int w = t >> 6, lane = t & 63, lid = lane & 15, quad = lane >> 4;

    #pragma unroll
    for (int part = 0; part < 8; part++) {
        const int cbase = part * 32 + w * 8;
        float tmp[8];
        #pragma unroll
        for (int cc = 0; cc < 8; cc++)
            tmp[cc] = x[(n * CIN + cbase + cc) * LL + l0 + lane];
        bf16x8 s;
        #pragma unroll
        for (int cc = 0; cc < 8; cc++) s[cc] = (short)f2bf(tmp[cc]);
        *(bf16x8*)&xlds[lane][cbase] = s;
    }
    __syncthreads();

    const f32x4 fzero = {0.f, 0.f, 0.f, 0.f};
    f32x4 acc[5][4];
    #pragma unroll
    for (int mt = 0; mt < 5; mt++)
        #pragma unroll
        for (int nt = 0; nt < 4; nt++) acc[mt][nt] = fzero;

    for (int k0 = 0; k0 < 256; k0 += 32) {
        bf16x8 bx[4];
        #pragma unroll
        for (int nt = 0; nt < 4; nt++)
            bx[nt] = *(const bf16x8*)&xlds[nt * 16 + lid][k0 + quad * 8];
        #pragma unroll
        for (int mt = 0; mt < 5; mt++) {
            const int row = (mt == 0) ? (w * 16 + lid) : (64 + w * 64 + (mt - 1) * 16 + lid);
            const bf16x8 wa = *(const bf16x8*)&Wb[row * 256 + k0 + quad * 8];
            #pragma unroll
            for (int nt = 0; nt < 4; nt++)
                acc[mt][nt] = __builtin_amdgcn_mfma_f32_16x16x32_bf16(wa, bx[nt], acc[mt][nt], 0, 0, 0);
        }
    }
    // v rows: direct stores (16 lanes contiguous in l per reg)
    #pragma unroll
    for (int mt = 1; mt < 5; mt++)
        #pragma unroll
        for (int nt = 0; nt < 4; nt++)
            #pragma unroll
            for (int reg = 0; reg < 4; reg++) {
                const int vr = w * 64 + (mt - 1) * 16 + quad * 4 + reg;
                v[((size_t)n * CV + vr) * LL + l0 + nt * 16 + lid] = f2bf(acc[mt][nt][reg]);
            }
    // qk rows: transpose through LDS, then coalesced 128B-row stores
    #pragma unroll
    for (int nt = 0; nt < 4; nt++)
        #pragma unroll
        for (int reg = 0; reg < 4; reg++)
            tr[nt * 16 + lid][w * 16 + quad * 4 + reg] = f2bf(acc[0][nt][reg]);
    __syncthreads();
    {
        const int l = t >> 2, c = (t & 3) * 16;
        uint4 d0 = *(const uint4*)&tr[l][c];
        uint4 d1 = *(const uint4*)&tr[l][c + 8];
        uint4* dst = (uint4*)&qkt[((size_t)n * LL + l0 + l) * 64 + c];
        dst[0] = d0; dst[1] = d1;
    }
}

// ---------------- K2: lns[i] = -log2( sum_j 2^(e2_ij) ), MFMA bf16 -------------
// grid (64, 8): i-tile 64, n. Wave w covers j = w*64 + jt*256 slices.
__global__ __launch_bounds__(256) void k_rowsum2(
    const unsigned short* __restrict__ qkt, float* __restrict__ lns)
{
    __shared__ float red[64];
    const int n = blockIdx.y, i0 = blockIdx.x * 64, t = threadIdx.x;
    const int w = t >> 6, lane = t & 63, lid = lane & 15, quad = lane >> 4;
    if (t < 64) red[t] = 0.f;
    __syncthreads();

    bf16x8 aq[4];
    #pragma unroll
    for (int mt = 0; mt < 4; mt++)
        aq[mt] = *(const bf16x8*)&qkt[((size_t)n * LL + i0 + mt * 16 + lid) * 64 + quad * 8];

    const f32x4 fzero = {0.f, 0.f, 0.f, 0.f};
    float sums[4][4];
    #pragma unroll
    for (int mt = 0; mt < 4; mt++)
        #pragma unroll
        for (int reg = 0; reg < 4; reg++) sums[mt][reg] = 0.f;

    for (int jt = 0; jt < 16; jt++) {
        const int j0 = jt * 256 + w * 64;
        bf16x8 bk[4];
        #pragma unroll
        for (int nt = 0; nt < 4; nt++)
            bk[nt] = *(const bf16x8*)&qkt[((size_t)n * LL + j0 + nt * 16 + lid) * 64 + 32 + quad * 8];
        #pragma unroll
        for (int mt = 0; mt < 4; mt++)
            #pragma unroll
            for (int nt = 0; nt < 4; nt++) {
                f32x4 e = __builtin_amdgcn_mfma_f32_16x16x32_bf16(aq[mt], bk[nt], fzero, 0, 0, 0);
                sums[mt][0] += __builtin_exp2f(e[0]);
                sums[mt][1] += __builtin_exp2f(e[1]);
                sums[mt][2] += __builtin_exp2f(e[2]);
                sums[mt][3] += __builtin_exp2f(e[3]);
            }
    }
    #pragma unroll
    for (int mt = 0; mt < 4; mt++)
        #pragma unroll
        for (int reg = 0; reg < 4; reg++) {
            float s = sums[mt][reg];
            s += __shfl_xor(s, 1); s += __shfl_xor(s, 2);
            s += __shfl_xor(s, 4); s += __shfl_xor(s, 8);
            if (lid == 0) atomicAdd(&red[mt * 16 + quad * 4 + reg], s);
        }
    __syncthreads();
    if (t < 64) lns[n * LL + i0 + t] = -__builtin_log2f(red[t]);
}

__device__ __forceinline__ void write_p(unsigned short (*pl)[64], const f32x4* e,
                                        int w, int lid, int quad, int xkey)
{
    #pragma unroll
    for (int nt = 0; nt < 4; nt++) {
        const unsigned a01 = f2bf2(__builtin_exp2f(e[nt][0]), __builtin_exp2f(e[nt][1]));
        const unsigned a23 = f2bf2(__builtin_exp2f(e[nt][2]), __builtin_exp2f(e[nt][3]));
        const int chunk = (2 * w + (quad >> 1)) ^ xkey;
        unsigned* p = (unsigned*)&pl[nt * 16 + lid][chunk * 8 + (quad & 1) * 4];
        p[0] = a01; p[1] = a23;
    }
}

// ---------------- K3: fused attention core, MFMA bf16 --------------------------
// grid (64, 8): j-tile 64, n. 4 waves; wave owns 64 v-rows, acc[4][4].
// Double-buffered swizzled P; lns folded into E-MFMA C; single barrier/iter.
__global__ __launch_bounds__(256) void k_attn3(
    const unsigned short* __restrict__ qkt, const unsigned short* __restrict__ v,
    const float* __restrict__ lns, unsigned short* __restrict__ o)
{
    __shared__ unsigned short plds[2][64][64];
    const int n = blockIdx.y, j0 = blockIdx.x * 64, t = threadIdx.x;
    const int w = t >> 6, lane = t & 63, lid = lane & 15, quad = lane >> 4;
    const int xkey = lid & 7;

    const unsigned short* qrow = qkt + ((size_t)n * LL + w * 16 + lid) * 64 + quad * 8;
    const float* lrow = lns + (size_t)n * LL + w * 16 + quad * 4;
    const unsigned short* vrow = v + ((size_t)n * CV + w * 64 + lid) * LL + quad * 8;

    bf16x8 bk[4];
    #pragma unroll
    for (int nt = 0; nt < 4; nt++)
        bk[nt] = *(const bf16x8*)&qkt[((size_t)n * LL + j0 + nt * 16 + lid) * 64 + 32 + quad * 8];

    const f32x4 fzero = {0.f, 0.f, 0.f, 0.f};
    f32x4 acc[4][4];
    #pragma unroll
    for (int mt = 0; mt < 4; mt++)
        #pragma unroll
        for (int nt = 0; nt < 4; nt++) acc[mt][nt] = fzero;

    // ---- prologue: E(0) -> P buf0; prefetch aq/lns(1); av(0) loads ----
    bf16x8 aq = *(const bf16x8*)qrow;
    f32x4 lnsC = *(const f32x4*)lrow;
    {
        f32x4 e[4];
        #pragma unroll
        for (int nt = 0; nt < 4; nt++)
            e[nt] = __builtin_amdgcn_mfma_f32_16x16x32_bf16(aq, bk[nt], lnsC, 0, 0, 0);
        aq = *(const bf16x8*)(qrow + (size_t)64 * 64);
        lnsC = *(const f32x4*)(lrow + 64);
        write_p(plds[0], e, w, lid, quad, xkey);
    }
    bf16x8 av[8];
    #pragma unroll
    for (int h = 0; h < 2; h++)
        #pragma unroll
        for (int mt = 0; mt < 4; mt++)
            av[h * 4 + mt] = *(const bf16x8*)(vrow + (size_t)mt * 16 * LL + h * 32);
    __syncthreads();

    for (int ic = 0; ic < 63; ic++) {
        const int cur = ic & 1;
        const size_t i0 = (size_t)ic * 64;
        // E-MFMAs for ic+1 (operands prefetched last iter)
        f32x4 e2[4];
        #pragma unroll
        for (int nt = 0; nt < 4; nt++)
            e2[nt] = __builtin_amdgcn_mfma_f32_16x16x32_bf16(aq, bk[nt], lnsC, 0, 0, 0);
        // prefetch aq/lns for ic+2 (clamped at the end; extra loads unused)
        const size_t ipf = (ic < 62) ? (i0 + 128) : i0;
        aq = *(const bf16x8*)(qrow + ipf * 64);
        lnsC = *(const f32x4*)(lrow + ipf);
        // O-phase on buf cur (av prefetched last iter)
        #pragma unroll
        for (int h = 0; h < 2; h++) {
            bf16x8 bp[4];
            #pragma unroll
            for (int nt = 0; nt < 4; nt++)
                bp[nt] = *(const bf16x8*)&plds[cur][nt * 16 + lid][((4 * h + quad) ^ xkey) * 8];
            #pragma unroll
            for (int mt = 0; mt < 4; mt++)
                #pragma unroll
                for (int nt = 0; nt < 4; nt++)
                    acc[mt][nt] = __builtin_amdgcn_mfma_f32_16x16x32_bf16(av[h * 4 + mt], bp[nt], acc[mt][nt], 0, 0, 0);
        }
        // reload av for ic+1 — latency absorbed by the barrier's vmcnt drain
        #pragma unroll
        for (int h = 0; h < 2; h++)
            #pragma unroll
            for (int mt = 0; mt < 4; mt++)
                av[h * 4 + mt] = *(const bf16x8*)(vrow + (size_t)mt * 16 * LL + (i0 + 64) + h * 32);
        // finish E: exp2 + pack + write P(ic+1) into buf cur^1
        write_p(plds[cur ^ 1], e2, w, lid, quad, xkey);
        __syncthreads();
    }
    // ---- final O-phase: ic=63, buf 1 ----
    #pragma unroll
    for (int h = 0; h < 2; h++) {
        bf16x8 bp[4];
        #pragma unroll
        for (int nt = 0; nt < 4; nt++)
            bp[nt] = *(const bf16x8*)&plds[1][nt * 16 + lid][((4 * h + quad) ^ xkey) * 8];
        #pragma unroll
        for (int mt = 0; mt < 4; mt++)
            #pragma unroll
            for (int nt = 0; nt < 4; nt++)
                acc[mt][nt] = __builtin_amdgcn_mfma_f32_16x16x32_bf16(av[h * 4 + mt], bp[nt], acc[mt][nt], 0, 0, 0);
    }
    #pragma unroll
    for (int mt = 0; mt < 4; mt++)
        #pragma unroll
        for (int nt = 0; nt < 4; nt++)
            #pragma unroll
            for (int reg = 0; reg < 4; reg++)
                o[((size_t)n * CV + w * 64 + mt * 16 + quad * 4 + reg) * LL + j0 + nt * 16 + lid] =
                    f2bf(acc[mt][nt][reg]);
}

// ---------------- K4: output projection + gamma, MFMA bf16 ---------------------
// grid (64, 8): l-tile 64, n. Wave owns 64 output rows.
__global__ __launch_bounds__(256) void k_out2(
    const unsigned short* __restrict__ o, const unsigned short* __restrict__ Wob,
    const float* __restrict__ gp, float* __restrict__ out)
{
    __shared__ unsigned short olds[64][264];   // [l][v]
    const int n = blockIdx.y, l0 = blockIdx.x * 64, t = threadIdx.x;
    const int w = t >> 6, lane = t & 63, lid = lane & 15, quad = lane >> 4;

    #pragma unroll
    for (int part = 0; part < 8; part++) {
        const int cbase = part * 32 + w * 8;
        bf16x8 s;
        #pragma unroll
        for (int cc = 0; cc < 8; cc++)
            s[cc] = (short)o[((size_t)n * CV + cbase + cc) * LL + l0 + lane];
        *(bf16x8*)&olds[lane][cbase] = s;
    }
    __syncthreads();

    const f32x4 fzero = {0.f, 0.f, 0.f, 0.f};
    f32x4 acc[4][4];
    #pragma unroll
    for (int mt = 0; mt < 4; mt++)
        #pragma unroll
        for (int nt = 0; nt < 4; nt++) acc[mt][nt] = fzero;

    for (int k0 = 0; k0 < 256; k0 += 32) {
        bf16x8 bo[4];
        #pragma unroll
        for (int nt = 0; nt < 4; nt++)
            bo[nt] = *(const bf16x8*)&olds[nt * 16 + lid][k0 + quad * 8];
        #pragma unroll
        for (int mt = 0; mt < 4; mt++) {
            const bf16x8 wa = *(const bf16x8*)&Wob[(w * 64 + mt * 16 + lid) * 256 + k0 + quad * 8];
            #pragma unroll
            for (int nt = 0; nt < 4; nt++)
                acc[mt][nt] = __builtin_amdgcn_mfma_f32_16x16x32_bf16(wa, bo[nt], acc[mt][nt], 0, 0, 0);
        }
    }
    const float g = *gp;
    #pragma unroll
    for (int mt = 0; mt < 4; mt++)
        #pragma unroll
        for (int nt = 0; nt < 4; nt++)
            #pragma unroll
            for (int reg = 0; reg < 4; reg++) {
                const int r = w * 64 + mt * 16 + quad * 4 + reg;
                out[((size_t)n * CIN + r) * LL + l0 + nt * 16 + lid] = g * acc[mt][nt][reg];
            }
}

extern "C" void kernel_launch(void* const* d_in, const int* in_sizes, int n_in,
                              void* d_out, int out_size, void* d_ws, size_t ws_size,
                              hipStream_t stream) {
    const float* x     = (const float*)d_in[0];
    const float* Wq    = (const float*)d_in[1];
    const float* Wk    = (const float*)d_in[2];
    const float* Wv    = (const float*)d_in[3];
    const float* Wo    = (const float*)d_in[4];
    const float* gamma = (const float*)d_in[5];

    unsigned short* qkt = (unsigned short*)d_ws;              // 4 MB
    unsigned short* v   = qkt + (size_t)NB * LL * 64;         // 16 MB
    unsigned short* o   = v + (size_t)NB * CV * LL;           // 16 MB
    unsigned short* Wb  = o + (size_t)NB * CV * LL;           // 160 KB
    unsigned short* Wob = Wb + 320 * 256;                     // 128 KB
    float* lns          = (float*)(Wob + 256 * 256);          // 128 KB
    float* out = (float*)d_out;

    k_wcast  <<<dim3(576),   256, 0, stream>>>(Wq, Wk, Wv, Wo, Wb, Wob);
    k_qkv2   <<<dim3(64, 8), 256, 0, stream>>>(x, Wb, qkt, v);
    k_rowsum2<<<dim3(64, 8), 256, 0, stream>>>(qkt, lns);
    k_attn3  <<<dim3(64, 8), 256, 0, stream>>>(qkt, v, lns, o);
    k_out2   <<<dim3(64, 8), 256, 0, stream>>>(o, Wob, gamma, out);
}

// Round 4
// 289.294 us; speedup vs baseline: 1.9348x; 1.0297x over previous
//
#include <hip/hip_runtime.h>
#include <hip/hip_bf16.h>

#define NB 8
#define CIN 256
#define LL 4096
#define CQ 32
#define CV 256

typedef __attribute__((ext_vector_type(8))) short bf16x8;
typedef __attribute__((ext_vector_type(4))) float f32x4;

__device__ __forceinline__ unsigned short f2bf(float f) {
    union { __hip_bfloat16 h; unsigned short u; } c;
    c.h = __float2bfloat16(f);
    return c.u;
}
__device__ __forceinline__ unsigned int f2bf2(float a, float b) {
    union { __hip_bfloat162 h; unsigned int u; } c;
    float2 f; f.x = a; f.y = b;
    c.h = __float22bfloat162_rn(f);
    return c.u;
}

// ---------------- K0: cast weights to bf16; Wq pre-scaled by log2(e) -----------
__global__ __launch_bounds__(256) void k_wcast(
    const float* __restrict__ Wq, const float* __restrict__ Wk,
    const float* __restrict__ Wv, const float* __restrict__ Wo,
    unsigned short* __restrict__ Wb, unsigned short* __restrict__ Wob)
{
    const float LOG2E = 1.4426950408889634f;
    const int row = blockIdx.x, t = threadIdx.x;
    if (row < 320) {
        float val;
        if (row < 32)      val = Wq[row * 256 + t] * LOG2E;
        else if (row < 64) val = Wk[(row - 32) * 256 + t];
        else               val = Wv[(row - 64) * 256 + t];
        Wb[row * 256 + t] = f2bf(val);
    } else {
        const int r2 = row - 320;
        Wob[r2 * 256 + t] = f2bf(Wo[r2 * 256 + t]);
    }
}

// ---------------- K1: fused QKV projection, MFMA bf16, 8 waves -----------------
// grid (64, 8), 512 thr. Wave w: v rows [64+w*32, 64+w*32+32); waves 0-3 also
// qk tile rows [w*16, w*16+16). qk stored transposed: qkt[n][l][64].
__global__ __launch_bounds__(512) void k_qkv3(
    const float* __restrict__ x, const unsigned short* __restrict__ Wb,
    unsigned short* __restrict__ qkt, unsigned short* __restrict__ v)
{
    __shared__ unsigned short xlds[64][264];
    __shared__ unsigned short tr[64][72];
    const int n = blockIdx.y, l0 = blockIdx.x * 64, t = threadIdx.x;
    const int w = t >> 6, lane = t & 63, lid = lane & 15, quad = lane >> 4;

    #pragma unroll
    for (int part = 0; part < 4; part++) {
        const int cbase = part * 64 + w * 8;
        float tmp[8];
        #pragma unroll
        for (int cc = 0; cc < 8; cc++)
            tmp[cc] = x[((size_t)n * CIN + cbase + cc) * LL + l0 + lane];
        bf16x8 s;
        #pragma unroll
        for (int cc = 0; cc < 8; cc++) s[cc] = (short)f2bf(tmp[cc]);
        *(bf16x8*)&xlds[lane][cbase] = s;
    }
    __syncthreads();

    const f32x4 fzero = {0.f, 0.f, 0.f, 0.f};
    f32x4 acc[3][4];
    #pragma unroll
    for (int mt = 0; mt < 3; mt++)
        #pragma unroll
        for (int nt = 0; nt < 4; nt++) acc[mt][nt] = fzero;

    for (int k0 = 0; k0 < 256; k0 += 32) {
        bf16x8 bx[4];
        #pragma unroll
        for (int nt = 0; nt < 4; nt++)
            bx[nt] = *(const bf16x8*)&xlds[nt * 16 + lid][k0 + quad * 8];
        #pragma unroll
        for (int vt = 0; vt < 2; vt++) {
            const bf16x8 wa = *(const bf16x8*)&Wb[(64 + w * 32 + vt * 16 + lid) * 256 + k0 + quad * 8];
            #pragma unroll
            for (int nt = 0; nt < 4; nt++)
                acc[vt][nt] = __builtin_amdgcn_mfma_f32_16x16x32_bf16(wa, bx[nt], acc[vt][nt], 0, 0, 0);
        }
        if (w < 4) {
            const bf16x8 wa = *(const bf16x8*)&Wb[(w * 16 + lid) * 256 + k0 + quad * 8];
            #pragma unroll
            for (int nt = 0; nt < 4; nt++)
                acc[2][nt] = __builtin_amdgcn_mfma_f32_16x16x32_bf16(wa, bx[nt], acc[2][nt], 0, 0, 0);
        }
    }
    #pragma unroll
    for (int vt = 0; vt < 2; vt++)
        #pragma unroll
        for (int nt = 0; nt < 4; nt++)
            #pragma unroll
            for (int reg = 0; reg < 4; reg++) {
                const int vr = w * 32 + vt * 16 + quad * 4 + reg;
                v[((size_t)n * CV + vr) * LL + l0 + nt * 16 + lid] = f2bf(acc[vt][nt][reg]);
            }
    if (w < 4) {
        #pragma unroll
        for (int nt = 0; nt < 4; nt++)
            #pragma unroll
            for (int reg = 0; reg < 4; reg++)
                tr[nt * 16 + lid][w * 16 + quad * 4 + reg] = f2bf(acc[2][nt][reg]);
    }
    __syncthreads();
    {
        const int l = t >> 3, c = (t & 7) * 8;
        *(uint4*)&qkt[((size_t)n * LL + l0 + l) * 64 + c] = *(const uint4*)&tr[l][c];
    }
}

// ---------------- K2: lns[i] = -log2( sum_j 2^(e2_ij) ), 8 waves ---------------
// grid (64, 8), 512 thr. Wave w covers j = jt*512 + w*64, jt 0..7.
__global__ __launch_bounds__(512) void k_rowsum3(
    const unsigned short* __restrict__ qkt, float* __restrict__ lns)
{
    __shared__ float red[64];
    const int n = blockIdx.y, i0 = blockIdx.x * 64, t = threadIdx.x;
    const int w = t >> 6, lid = t & 15, quad = (t & 63) >> 4;
    if (t < 64) red[t] = 0.f;
    __syncthreads();

    bf16x8 aq[4];
    #pragma unroll
    for (int mt = 0; mt < 4; mt++)
        aq[mt] = *(const bf16x8*)&qkt[((size_t)n * LL + i0 + mt * 16 + lid) * 64 + quad * 8];

    const f32x4 fzero = {0.f, 0.f, 0.f, 0.f};
    float sums[4][4];
    #pragma unroll
    for (int mt = 0; mt < 4; mt++)
        #pragma unroll
        for (int reg = 0; reg < 4; reg++) sums[mt][reg] = 0.f;

    for (int jt = 0; jt < 8; jt++) {
        const int j0 = jt * 512 + w * 64;
        bf16x8 bk[4];
        #pragma unroll
        for (int nt = 0; nt < 4; nt++)
            bk[nt] = *(const bf16x8*)&qkt[((size_t)n * LL + j0 + nt * 16 + lid) * 64 + 32 + quad * 8];
        #pragma unroll
        for (int mt = 0; mt < 4; mt++)
            #pragma unroll
            for (int nt = 0; nt < 4; nt++) {
                f32x4 e = __builtin_amdgcn_mfma_f32_16x16x32_bf16(aq[mt], bk[nt], fzero, 0, 0, 0);
                sums[mt][0] += __builtin_exp2f(e[0]);
                sums[mt][1] += __builtin_exp2f(e[1]);
                sums[mt][2] += __builtin_exp2f(e[2]);
                sums[mt][3] += __builtin_exp2f(e[3]);
            }
    }
    #pragma unroll
    for (int mt = 0; mt < 4; mt++)
        #pragma unroll
        for (int reg = 0; reg < 4; reg++) {
            float s = sums[mt][reg];
            s += __shfl_xor(s, 1); s += __shfl_xor(s, 2);
            s += __shfl_xor(s, 4); s += __shfl_xor(s, 8);
            if (lid == 0) atomicAdd(&red[mt * 16 + quad * 4 + reg], s);
        }
    __syncthreads();
    if (t < 64) lns[(size_t)n * LL + i0 + t] = -__builtin_log2f(red[t]);
}

__device__ __forceinline__ void write_p(unsigned short (*pl)[128], const f32x4* e,
                                        int w, int lid, int quad, int xkey)
{
    const int chunk = (2 * w + (quad >> 1)) ^ xkey;
    #pragma unroll
    for (int nt = 0; nt < 4; nt++) {
        const unsigned a01 = f2bf2(__builtin_exp2f(e[nt][0]), __builtin_exp2f(e[nt][1]));
        const unsigned a23 = f2bf2(__builtin_exp2f(e[nt][2]), __builtin_exp2f(e[nt][3]));
        unsigned* p = (unsigned*)&pl[nt * 16 + lid][chunk * 8 + (quad & 1) * 4];
        p[0] = a01; p[1] = a23;
    }
}

// ---------------- K3: fused attention core + output projection ----------------
// grid (512) 1D, 512 thr (8 waves). n = bid&7 (XCD-locality), j-tile = bid>>3.
// i-chunk 128/iter, 32 iters. Wave: 16 E-rows, 32 V-rows (acc[2][4]).
// Epilogue: o-tile (256x64) -> LDS -> Wo GEMM -> gamma -> fp32 out.
__global__ __launch_bounds__(512, 4) void k_attn4(
    const unsigned short* __restrict__ qkt, const unsigned short* __restrict__ v,
    const float* __restrict__ lns, const unsigned short* __restrict__ Wob,
    const float* __restrict__ gp, float* __restrict__ out)
{
    __shared__ unsigned short lraw[64 * 264];   // 33792 B: P dbuf (32KB) / olds
    unsigned short (*plds)[64][128] = (unsigned short (*)[64][128])lraw;
    unsigned short (*olds)[264] = (unsigned short (*)[264])lraw;

    const int bid = blockIdx.x;
    const int n = bid & 7, j0 = (bid >> 3) * 64, t = threadIdx.x;
    const int w = t >> 6, lane = t & 63, lid = lane & 15, quad = lane >> 4;
    const int xkey = lid & 7;

    const unsigned short* qrow = qkt + ((size_t)n * LL + w * 16 + lid) * 64 + quad * 8;
    const float* lrow = lns + (size_t)n * LL + w * 16 + quad * 4;
    const unsigned short* vrow = v + ((size_t)n * CV + w * 32 + lid) * LL + quad * 8;

    bf16x8 bk[4];
    #pragma unroll
    for (int nt = 0; nt < 4; nt++)
        bk[nt] = *(const bf16x8*)&qkt[((size_t)n * LL + j0 + nt * 16 + lid) * 64 + 32 + quad * 8];

    const f32x4 fzero = {0.f, 0.f, 0.f, 0.f};
    f32x4 acc[2][4];
    #pragma unroll
    for (int mt = 0; mt < 2; mt++)
        #pragma unroll
        for (int nt = 0; nt < 4; nt++) acc[mt][nt] = fzero;

    // ---- prologue ----
    bf16x8 aq = *(const bf16x8*)qrow;
    f32x4 lnsC = *(const f32x4*)lrow;
    {
        f32x4 e[4];
        #pragma unroll
        for (int nt = 0; nt < 4; nt++)
            e[nt] = __builtin_amdgcn_mfma_f32_16x16x32_bf16(aq, bk[nt], lnsC, 0, 0, 0);
        aq = *(const bf16x8*)(qrow + (size_t)128 * 64);
        lnsC = *(const f32x4*)(lrow + 128);
        write_p(plds[0], e, w, lid, quad, xkey);
    }
    bf16x8 av[8];   // [mt*4+h]
    #pragma unroll
    for (int mt = 0; mt < 2; mt++)
        #pragma unroll
        for (int h = 0; h < 4; h++)
            av[mt * 4 + h] = *(const bf16x8*)(vrow + (size_t)mt * 16 * LL + h * 32);
    __syncthreads();

    for (int ic = 0; ic < 31; ic++) {
        const int cur = ic & 1;
        const size_t i0 = (size_t)ic * 128;
        // E for ic+1
        f32x4 e2[4];
        #pragma unroll
        for (int nt = 0; nt < 4; nt++)
            e2[nt] = __builtin_amdgcn_mfma_f32_16x16x32_bf16(aq, bk[nt], lnsC, 0, 0, 0);
        const size_t ipf = (ic < 30) ? (i0 + 256) : i0;
        aq = *(const bf16x8*)(qrow + ipf * 64);
        lnsC = *(const f32x4*)(lrow + ipf);
        write_p(plds[cur ^ 1], e2, w, lid, quad, xkey);
        // O-phase on buf cur
        #pragma unroll
        for (int h = 0; h < 4; h++) {
            bf16x8 bp[4];
            #pragma unroll
            for (int nt = 0; nt < 4; nt++)
                bp[nt] = *(const bf16x8*)&plds[cur][nt * 16 + lid][((4 * h + quad) ^ xkey) * 8];
            #pragma unroll
            for (int mt = 0; mt < 2; mt++)
                #pragma unroll
                for (int nt = 0; nt < 4; nt++)
                    acc[mt][nt] = __builtin_amdgcn_mfma_f32_16x16x32_bf16(av[mt * 4 + h], bp[nt], acc[mt][nt], 0, 0, 0);
        }
        // av for ic+1 — latency absorbed by barrier drain
        #pragma unroll
        for (int mt = 0; mt < 2; mt++)
            #pragma unroll
            for (int h = 0; h < 4; h++)
                av[mt * 4 + h] = *(const bf16x8*)(vrow + (size_t)mt * 16 * LL + (i0 + 128) + h * 32);
        __syncthreads();
    }
    // ---- final O-phase: ic=31, buf 1 ----
    #pragma unroll
    for (int h = 0; h < 4; h++) {
        bf16x8 bp[4];
        #pragma unroll
        for (int nt = 0; nt < 4; nt++)
            bp[nt] = *(const bf16x8*)&plds[1][nt * 16 + lid][((4 * h + quad) ^ xkey) * 8];
        #pragma unroll
        for (int mt = 0; mt < 2; mt++)
            #pragma unroll
            for (int nt = 0; nt < 4; nt++)
                acc[mt][nt] = __builtin_amdgcn_mfma_f32_16x16x32_bf16(av[mt * 4 + h], bp[nt], acc[mt][nt], 0, 0, 0);
    }
    __syncthreads();   // all P reads done; reuse LDS as olds

    // ---- epilogue: o-tile -> olds[j][v] ----
    #pragma unroll
    for (int mt = 0; mt < 2; mt++)
        #pragma unroll
        for (int nt = 0; nt < 4; nt++) {
            ushort4 s;
            s.x = f2bf(acc[mt][nt][0]); s.y = f2bf(acc[mt][nt][1]);
            s.z = f2bf(acc[mt][nt][2]); s.w = f2bf(acc[mt][nt][3]);
            *(ushort4*)&olds[nt * 16 + lid][w * 32 + mt * 16 + quad * 4] = s;
        }
    __syncthreads();
    // out rows [w*32, w*32+32) x 64 l
    f32x4 oacc[2][4];
    #pragma unroll
    for (int mt = 0; mt < 2; mt++)
        #pragma unroll
        for (int nt = 0; nt < 4; nt++) oacc[mt][nt] = fzero;
    for (int k0 = 0; k0 < 256; k0 += 32) {
        bf16x8 bo[4];
        #pragma unroll
        for (int nt = 0; nt < 4; nt++)
            bo[nt] = *(const bf16x8*)&olds[nt * 16 + lid][k0 + quad * 8];
        #pragma unroll
        for (int mt = 0; mt < 2; mt++) {
            const bf16x8 wa = *(const bf16x8*)&Wob[(w * 32 + mt * 16 + lid) * 256 + k0 + quad * 8];
            #pragma unroll
            for (int nt = 0; nt < 4; nt++)
                oacc[mt][nt] = __builtin_amdgcn_mfma_f32_16x16x32_bf16(wa, bo[nt], oacc[mt][nt], 0, 0, 0);
        }
    }
    const float g = *gp;
    #pragma unroll
    for (int mt = 0; mt < 2; mt++)
        #pragma unroll
        for (int nt = 0; nt < 4; nt++)
            #pragma unroll
            for (int reg = 0; reg < 4; reg++) {
                const int r = w * 32 + mt * 16 + quad * 4 + reg;
                out[((size_t)n * CIN + r) * LL + j0 + nt * 16 + lid] = g * oacc[mt][nt][reg];
            }
}

extern "C" void kernel_launch(void* const* d_in, const int* in_sizes, int n_in,
                              void* d_out, int out_size, void* d_ws, size_t ws_size,
                              hipStream_t stream) {
    const float* x     = (const float*)d_in[0];
    const float* Wq    = (const float*)d_in[1];
    const float* Wk    = (const float*)d_in[2];
    const float* Wv    = (const float*)d_in[3];
    const float* Wo    = (const float*)d_in[4];
    const float* gamma = (const float*)d_in[5];

    unsigned short* qkt = (unsigned short*)d_ws;              // 4 MB
    unsigned short* v   = qkt + (size_t)NB * LL * 64;         // 16 MB
    unsigned short* Wb  = v + (size_t)NB * CV * LL;           // 160 KB
    unsigned short* Wob = Wb + 320 * 256;                     // 128 KB
    float* lns          = (float*)(Wob + 256 * 256);          // 128 KB
    float* out = (float*)d_out;

    k_wcast  <<<dim3(576),   256, 0, stream>>>(Wq, Wk, Wv, Wo, Wb, Wob);
    k_qkv3   <<<dim3(64, 8), 512, 0, stream>>>(x, Wb, qkt, v);
    k_rowsum3<<<dim3(64, 8), 512, 0, stream>>>(qkt, lns);
    k_attn4  <<<dim3(512),   512, 0, stream>>>(qkt, v, lns, Wob, gamma, out);
}